// Round 11
// baseline (29.312 us; speedup 1.0000x reference)
//
#include <hip/hip_runtime.h>
#include <math.h>

#define NB 64
#define NS 4096
#define SEGS 8                   // segments per batch
#define K1_TPB 512               // k1: 1 element per thread
#define K1_W (K1_TPB / 64)       // 8
#define STEPS (NS / SEGS)        // 512 elements per segment
#define NSEGB (NB * SEGS)        // 512 blocks
#define K3_TPB 512
#define K3_W (K3_TPB / 64)
#define FTPB 512

// fallback (single-phase) params
#define FB_T 512
#define FB_CHUNK (NS / FB_T)
#define FB_W (FB_T / 64)

// ---------------- quaternion + translation rigid transform -----------------
struct Q {
  float w, x, y, z;
};
struct QT {
  Q q;
  float tx, ty, tz;
};

__device__ __forceinline__ Q qmul(const Q &a, const Q &b) {
  Q c;
  c.w = a.w * b.w - a.x * b.x - a.y * b.y - a.z * b.z;
  c.x = a.w * b.x + b.w * a.x + a.y * b.z - a.z * b.y;
  c.y = a.w * b.y + b.w * a.y + a.z * b.x - a.x * b.z;
  c.z = a.w * b.z + b.w * a.z + a.x * b.y - a.y * b.x;
  return c;
}

__device__ __forceinline__ Q qconj(const Q &q) {
  Q c;
  c.w = q.w;
  c.x = -q.x;
  c.y = -q.y;
  c.z = -q.z;
  return c;
}

// rotate (vx,vy,vz) by q
__device__ __forceinline__ void qrot(const Q &q, float vx, float vy, float vz,
                                     float &ox, float &oy, float &oz) {
  const float tx = 2.f * (q.y * vz - q.z * vy);
  const float ty = 2.f * (q.z * vx - q.x * vz);
  const float tz = 2.f * (q.x * vy - q.y * vx);
  ox = vx + q.w * tx + (q.y * tz - q.z * ty);
  oy = vy + q.w * ty + (q.z * tx - q.x * tz);
  oz = vz + q.w * tz + (q.x * ty - q.y * tx);
}

__device__ __forceinline__ void qt_id(QT &x) {
  x.q.w = 1.f;
  x.q.x = x.q.y = x.q.z = 0.f;
  x.tx = x.ty = x.tz = 0.f;
}

// c = a * b : q = qa*qb, t = rot(qa, tb) + ta
__device__ __forceinline__ QT qt_mul(const QT &a, const QT &b) {
  QT c;
  c.q = qmul(a.q, b.q);
  float rx, ry, rz;
  qrot(a.q, b.tx, b.ty, b.tz, rx, ry, rz);
  c.tx = rx + a.tx;
  c.ty = ry + a.ty;
  c.tz = rz + a.tz;
  return c;
}

__device__ __forceinline__ QT qt_shfl_up(const QT &v, int delta) {
  QT y;
  y.q.w = __shfl_up(v.q.w, delta, 64);
  y.q.x = __shfl_up(v.q.x, delta, 64);
  y.q.y = __shfl_up(v.q.y, delta, 64);
  y.q.z = __shfl_up(v.q.z, delta, 64);
  y.tx = __shfl_up(v.tx, delta, 64);
  y.ty = __shfl_up(v.ty, delta, 64);
  y.tz = __shfl_up(v.tz, delta, 64);
  return y;
}

// fast acos: Abramowitz-Stegun 4.4.45 style, |err| <= 6.7e-5 rad
__device__ __forceinline__ float fast_acosf(float x) {
  const float ax = fabsf(x);
  float p = fmaf(ax, -0.0187293f, 0.0742610f);
  p = fmaf(p, ax, -0.2121144f);
  p = fmaf(p, ax, 1.5707288f);
  const float r = sqrtf(fmaxf(1.f - ax, 0.f)) * p;
  return (x >= 0.f) ? r : (3.14159274f - r);
}

__device__ __forceinline__ float angle_from_cos(float cosv) {
  cosv = fminf(fmaxf(cosv, -1.f + 1e-6f), 1.f - 1e-6f);
  return fast_acosf(cosv);
}

// Euler xyz (R = Rz(c)*Ry(b)*Rx(a)) -> quaternion, via half angles
__device__ __forceinline__ Q euler_to_quat(float a, float b, float c) {
  float sa, ca, sb, cb, sc, cc;
  __sincosf(0.5f * a, &sa, &ca);
  __sincosf(0.5f * b, &sb, &cb);
  __sincosf(0.5f * c, &sc, &cc);
  Q q;
  q.w = cc * cb * ca + sc * sb * sa;
  q.x = cc * cb * sa - sc * sb * ca;
  q.y = cc * sb * ca + sc * cb * sa;
  q.z = sc * cb * ca - cc * sb * sa;
  return q;
}

__device__ __forceinline__ void block_reduce3_store(float v0, float v1,
                                                    float v2,
                                                    float *__restrict__ dst,
                                                    int lane, int wave,
                                                    int tid, int nwaves) {
#pragma unroll
  for (int o = 32; o > 0; o >>= 1) {
    v0 += __shfl_xor(v0, o, 64);
    v1 += __shfl_xor(v1, o, 64);
    v2 += __shfl_xor(v2, o, 64);
  }
  __shared__ float red[8][3];
  if (lane == 0) {
    red[wave][0] = v0;
    red[wave][1] = v1;
    red[wave][2] = v2;
  }
  __syncthreads();
  if (tid == 0) {
    float a = 0.f, b = 0.f, c = 0.f;
    for (int w = 0; w < nwaves; ++w) {
      a += red[w][0];
      b += red[w][1];
      c += red[w][2];
    }
    dst[0] = a;
    dst[1] = b;
    dst[2] = c;
  }
}

// ws layout (floats):
//   wsl   : NB * 10 * NS  per-step {q_rel(4) | lt(3),gt.x | gt.y,gt.z} SoA
//   aggs  : NSEGB * 16    segment-end QT pairs (est 7 | pad | gt 7 | pad)
//   part1 : NSEGB * 3
//   part2 : NSEGB * 3

// ---------------- k1: dual-chain quaternion scan, 1 elem/thread ------------
__global__ __launch_bounds__(K1_TPB) void k1_scan(
    const float *__restrict__ y_hat, const float *__restrict__ gt_pos,
    const float *__restrict__ gt_ori, float *__restrict__ wsl,
    float *__restrict__ aggs, float *__restrict__ part1) {
  const int blk = blockIdx.x;
  const int b = blk >> 3;
  const int seg = blk & (SEGS - 1);
  const int tid = threadIdx.x;
  const int lane = tid & 63;
  const int wave = tid >> 6;
  const int s = seg * STEPS + tid;

  float s_sq, s_abs, s_rot;

  QT Pe, Pg;
  {
    const float *y6 = y_hat + ((size_t)b * NS + s) * 6;
    const float *g3 = gt_pos + ((size_t)b * NS + s) * 3;
    const float *o3 = gt_ori + ((size_t)b * NS + s) * 3;
    const float px = y6[3], py = y6[4], pz = y6[5];
    const float gx = g3[0], gy = g3[1], gz = g3[2];
    Pe.q = euler_to_quat(y6[0], y6[1], y6[2]);
    Pe.tx = px; Pe.ty = py; Pe.tz = pz;
    Pg.q = euler_to_quat(o3[0], o3[1], o3[2]);
    Pg.tx = gx; Pg.ty = gy; Pg.tz = gz;
    const float dx = px - gx, dy = py - gy, dz = pz - gz;
    s_sq = dx * dx + dy * dy + dz * dz;
    s_abs = fabsf(dx) + fabsf(dy) + fabsf(dz);
    const float d = Pe.q.w * Pg.q.w + Pe.q.x * Pg.q.x + Pe.q.y * Pg.q.y +
                    Pe.q.z * Pg.q.z;
    s_rot = angle_from_cos(2.f * d * d - 1.f);
    if (s == 0) {  // shifted[0] = identity
      qt_id(Pe);
      qt_id(Pg);
    }
  }

  // dual-chain wave Kogge-Stone inclusive scan
  QT Ie = Pe, Ig = Pg;
#pragma unroll
  for (int o = 1; o < 64; o <<= 1) {
    QT pe = qt_shfl_up(Ie, o);
    QT pg = qt_shfl_up(Ig, o);
    if (lane >= o) {
      Ie = qt_mul(pe, Ie);
      Ig = qt_mul(pg, Ig);
    }
  }

  // cross-wave prefix (7 floats per chain)
  __shared__ float aggE[K1_W][8];
  __shared__ float aggG[K1_W][8];
  if (lane == 63) {
    aggE[wave][0] = Ie.q.w; aggE[wave][1] = Ie.q.x;
    aggE[wave][2] = Ie.q.y; aggE[wave][3] = Ie.q.z;
    aggE[wave][4] = Ie.tx; aggE[wave][5] = Ie.ty; aggE[wave][6] = Ie.tz;
    aggG[wave][0] = Ig.q.w; aggG[wave][1] = Ig.q.x;
    aggG[wave][2] = Ig.q.y; aggG[wave][3] = Ig.q.z;
    aggG[wave][4] = Ig.tx; aggG[wave][5] = Ig.ty; aggG[wave][6] = Ig.tz;
  }
  __syncthreads();

  QT We, Wg;
  qt_id(We);
  qt_id(Wg);
  for (int w = 0; w < wave; ++w) {
    QT ae, ag;
    ae.q.w = aggE[w][0]; ae.q.x = aggE[w][1];
    ae.q.y = aggE[w][2]; ae.q.z = aggE[w][3];
    ae.tx = aggE[w][4]; ae.ty = aggE[w][5]; ae.tz = aggE[w][6];
    ag.q.w = aggG[w][0]; ag.q.x = aggG[w][1];
    ag.q.y = aggG[w][2]; ag.q.z = aggG[w][3];
    ag.tx = aggG[w][4]; ag.ty = aggG[w][5]; ag.tz = aggG[w][6];
    We = qt_mul(We, ae);
    Wg = qt_mul(Wg, ag);
  }

  // thread's block-local inclusive prefix at step s (no exclusive shift)
  QT Le = qt_mul(We, Ie);
  QT Lg = qt_mul(Wg, Ig);

  // per-step compressed record
  float4 *q4 = (float4 *)(wsl + (size_t)b * 10 * NS);
  float4 *lt4 = q4 + NS;
  float2 *g2 = (float2 *)(lt4 + NS);
  {
    const Q qm = qmul(Le.q, qconj(Lg.q));
    q4[s] = make_float4(qm.w, qm.x, qm.y, qm.z);
    lt4[s] = make_float4(Le.tx, Le.ty, Le.tz, Lg.tx);
    g2[s] = make_float2(Lg.ty, Lg.tz);
  }

  // segment aggregate (QT pair) for k3's prefix walk
  if (tid == K1_TPB - 1) {
    float *ag = aggs + (size_t)blk * 16;
    ag[0] = Le.q.w; ag[1] = Le.q.x; ag[2] = Le.q.y; ag[3] = Le.q.z;
    ag[4] = Le.tx; ag[5] = Le.ty; ag[6] = Le.tz;
    ag[8] = Lg.q.w; ag[9] = Lg.q.x; ag[10] = Lg.q.y; ag[11] = Lg.q.z;
    ag[12] = Lg.tx; ag[13] = Lg.ty; ag[14] = Lg.tz;
  }

  block_reduce3_store(s_sq, s_abs, s_rot, part1 + (size_t)blk * 3, lane, wave,
                      tid, K1_W);
}

// ---------------- k3: contracted traj terms -------------------------------
__global__ __launch_bounds__(K3_TPB) void k3_traj(const float *__restrict__ wsl,
                                                  const float *__restrict__ aggs,
                                                  float *__restrict__ part2) {
  const int blk = blockIdx.x;
  const int b = blk >> 3;
  const int seg = blk & (SEGS - 1);
  const int tid = threadIdx.x;
  const int lane = tid & 63;
  const int wave = tid >> 6;
  const int s = seg * STEPS + tid;

  // segment-exclusive prefixes (block-uniform walk over <=7 aggregates)
  QT Ee, Eg;
  qt_id(Ee);
  qt_id(Eg);
  const float *abase = aggs + (size_t)(b * SEGS) * 16;
  for (int w = 0; w < seg; ++w) {
    const float *ag = abase + (size_t)w * 16;
    QT ae, agm;
    ae.q.w = ag[0]; ae.q.x = ag[1]; ae.q.y = ag[2]; ae.q.z = ag[3];
    ae.tx = ag[4]; ae.ty = ag[5]; ae.tz = ag[6];
    agm.q.w = ag[8]; agm.q.x = ag[9]; agm.q.y = ag[10]; agm.q.z = ag[11];
    agm.tx = ag[12]; agm.ty = ag[13]; agm.tz = ag[14];
    Ee = qt_mul(Ee, ae);
    Eg = qt_mul(Eg, agm);
  }

  // block-uniform u = conj(q_Eg) * q_Ee ; dt0 = Ee.t - Eg.t
  const Q u = qmul(qconj(Eg.q), Ee.q);
  const float dt0x = Ee.tx - Eg.tx;
  const float dt0y = Ee.ty - Eg.ty;
  const float dt0z = Ee.tz - Eg.tz;

  // per-step record
  const float4 *q4 = (const float4 *)(wsl + (size_t)b * 10 * NS);
  const float4 *lt4 = q4 + NS;
  const float2 *g2 = (const float2 *)(lt4 + NS);
  const float4 qm = q4[s];
  const float4 lt = lt4[s];
  const float2 gv = g2[s];

  // rotation: w(q_Ee * qm * conj(q_Eg)) has cos = 2*wd^2 - 1,
  // wd = w(u * qm) with u block-uniform; qm stored (w,x,y,z)
  const float mw = qm.x, mx = qm.y, my = qm.z, mz = qm.w;
  const float wd = u.w * mw - u.x * mx - u.y * my - u.z * mz;
  float s_rot = angle_from_cos(2.f * wd * wd - 1.f);

  // position: d = rot(Ee.q, lt) - rot(Eg.q, gt) + dt0
  float ux, uy, uz, vx, vy, vz;
  qrot(Ee.q, lt.x, lt.y, lt.z, ux, uy, uz);
  qrot(Eg.q, lt.w, gv.x, gv.y, vx, vy, vz);
  const float dx = ux - vx + dt0x;
  const float dy = uy - vy + dt0y;
  const float dz = uz - vz + dt0z;

  float s_sq = dx * dx + dy * dy + dz * dz;
  float s_abs = fabsf(dx) + fabsf(dy) + fabsf(dz);

  block_reduce3_store(s_sq, s_abs, s_rot, part2 + (size_t)blk * 3, lane, wave,
                      tid, K3_W);
}

__global__ __launch_bounds__(FTPB) void finalize_parts(
    const float *__restrict__ part1, const float *__restrict__ part2,
    float *__restrict__ out) {
  const int tid = threadIdx.x;
  const int lane = tid & 63;
  const int wave = tid >> 6;

  float v[6];
#pragma unroll
  for (int k = 0; k < 3; ++k) {
    v[k] = part1[(size_t)tid * 3 + k];
    v[3 + k] = part2[(size_t)tid * 3 + k];
  }
#pragma unroll
  for (int o = 32; o > 0; o >>= 1) {
#pragma unroll
    for (int k = 0; k < 6; ++k) v[k] += __shfl_xor(v[k], o, 64);
  }
  __shared__ float red[FTPB / 64][6];
  if (lane == 0) {
#pragma unroll
    for (int k = 0; k < 6; ++k) red[wave][k] = v[k];
  }
  __syncthreads();
  if (tid == 0) {
    double a[6];
#pragma unroll
    for (int k = 0; k < 6; ++k) {
      double t = 0.0;
#pragma unroll
      for (int w = 0; w < FTPB / 64; ++w) t += (double)red[w][k];
      a[k] = t;
    }
    const double n3 = (double)NB * (double)NS * 3.0;
    const double n1 = (double)NB * (double)NS;
    const double odom = a[2] / n1 + (a[0] / n3 + a[1] / n3);
    const double traj = a[5] / n1 + (a[3] / n3 + a[4] / n3);
    out[0] = (float)(0.5 * odom + 0.5 * traj);
  }
}

// ---------------- fallback single-phase path (matrices, tiny ws) -----------
struct SE3 {
  float r[9];
  float t[3];
};

__device__ __forceinline__ void se3_id(SE3 &x) {
#pragma unroll
  for (int i = 0; i < 9; ++i) x.r[i] = 0.f;
  x.r[0] = x.r[4] = x.r[8] = 1.f;
  x.t[0] = x.t[1] = x.t[2] = 0.f;
}

__device__ __forceinline__ SE3 se3_mul(const SE3 &a, const SE3 &b) {
  SE3 c;
#pragma unroll
  for (int i = 0; i < 3; ++i) {
#pragma unroll
    for (int j = 0; j < 3; ++j) {
      c.r[i * 3 + j] = fmaf(a.r[i * 3 + 0], b.r[0 * 3 + j],
                       fmaf(a.r[i * 3 + 1], b.r[1 * 3 + j],
                            a.r[i * 3 + 2] * b.r[2 * 3 + j]));
    }
    c.t[i] = fmaf(a.r[i * 3 + 0], b.t[0],
             fmaf(a.r[i * 3 + 1], b.t[1],
             fmaf(a.r[i * 3 + 2], b.t[2], a.t[i])));
  }
  return c;
}

__device__ __forceinline__ SE3 build_pose(float a, float b, float c,
                                          float tx, float ty, float tz) {
  float sa, ca, sb, cb, sc, cc;
  __sincosf(a, &sa, &ca);
  __sincosf(b, &sb, &cb);
  __sincosf(c, &sc, &cc);
  SE3 p;
  p.r[0] = cc * cb;
  p.r[1] = cc * sb * sa - sc * ca;
  p.r[2] = cc * sb * ca + sc * sa;
  p.r[3] = sc * cb;
  p.r[4] = sc * sb * sa + cc * ca;
  p.r[5] = sc * sb * ca - cc * sa;
  p.r[6] = -sb;
  p.r[7] = cb * sa;
  p.r[8] = cb * ca;
  p.t[0] = tx;
  p.t[1] = ty;
  p.t[2] = tz;
  return p;
}

__device__ __forceinline__ SE3 se3_shfl_up(const SE3 &x, int delta) {
  SE3 y;
#pragma unroll
  for (int i = 0; i < 9; ++i) y.r[i] = __shfl_up(x.r[i], delta, 64);
#pragma unroll
  for (int i = 0; i < 3; ++i) y.t[i] = __shfl_up(x.t[i], delta, 64);
  return y;
}

__device__ __forceinline__ float geo_angle(const SE3 &A, const SE3 &B) {
  float dot = 0.f;
#pragma unroll
  for (int k = 0; k < 9; ++k) dot = fmaf(A.r[k], B.r[k], dot);
  return angle_from_cos(0.5f * (dot - 1.f));
}

__global__ __launch_bounds__(FB_T) void traj_loss_main(
    const float *__restrict__ y_hat, const float *__restrict__ gt_pos,
    const float *__restrict__ gt_ori, double *__restrict__ acc) {
  const int b = blockIdx.x;
  const int tid = threadIdx.x;
  const int lane = tid & 63;
  const int wave = tid >> 6;
  const int s0 = tid * FB_CHUNK;

  const float *yb = y_hat + (size_t)b * NS * 6;
  const float *gp = gt_pos + (size_t)b * NS * 3;
  const float *go = gt_ori + (size_t)b * NS * 3;

  float s_sq_pos = 0.f, s_abs_pos = 0.f, s_rot_odom = 0.f;

  SE3 Le, Lg;
  se3_id(Le);
  se3_id(Lg);

  for (int i = 0; i < FB_CHUNK; ++i) {
    const int s = s0 + i;
    const float *y6 = yb + (size_t)s * 6;
    const float *g3 = gp + (size_t)s * 3;
    const float *o3 = go + (size_t)s * 3;
    const float px = y6[3], py = y6[4], pz = y6[5];
    const float gx = g3[0], gy = g3[1], gz = g3[2];

    SE3 Pe = build_pose(y6[0], y6[1], y6[2], px, py, pz);
    SE3 Pg = build_pose(o3[0], o3[1], o3[2], gx, gy, gz);

    const float dx = px - gx, dy = py - gy, dz = pz - gz;
    s_sq_pos += dx * dx + dy * dy + dz * dz;
    s_abs_pos += fabsf(dx) + fabsf(dy) + fabsf(dz);
    s_rot_odom += geo_angle(Pe, Pg);

    if (s != 0) {
      Le = se3_mul(Le, Pe);
      Lg = se3_mul(Lg, Pg);
    }
  }

  SE3 Ie = Le, Ig = Lg;
#pragma unroll
  for (int o = 1; o < 64; o <<= 1) {
    SE3 pe = se3_shfl_up(Ie, o);
    SE3 pg = se3_shfl_up(Ig, o);
    if (lane >= o) {
      Ie = se3_mul(pe, Ie);
      Ig = se3_mul(pg, Ig);
    }
  }

  __shared__ float aggE[FB_W][12];
  __shared__ float aggG[FB_W][12];
  if (lane == 63) {
#pragma unroll
    for (int k = 0; k < 9; ++k) {
      aggE[wave][k] = Ie.r[k];
      aggG[wave][k] = Ig.r[k];
    }
#pragma unroll
    for (int k = 0; k < 3; ++k) {
      aggE[wave][9 + k] = Ie.t[k];
      aggG[wave][9 + k] = Ig.t[k];
    }
  }
  __syncthreads();

  SE3 Te, Tg;
  se3_id(Te);
  se3_id(Tg);
  for (int w = 0; w < wave; ++w) {
    SE3 ae, ag;
#pragma unroll
    for (int k = 0; k < 9; ++k) {
      ae.r[k] = aggE[w][k];
      ag.r[k] = aggG[w][k];
    }
#pragma unroll
    for (int k = 0; k < 3; ++k) {
      ae.t[k] = aggE[w][9 + k];
      ag.t[k] = aggG[w][9 + k];
    }
    Te = se3_mul(Te, ae);
    Tg = se3_mul(Tg, ag);
  }

  SE3 Ee = se3_shfl_up(Ie, 1);
  SE3 Eg = se3_shfl_up(Ig, 1);
  if (lane == 0) {
    se3_id(Ee);
    se3_id(Eg);
  }
  Te = se3_mul(Te, Ee);
  Tg = se3_mul(Tg, Eg);

  float s_sq_tr = 0.f, s_abs_tr = 0.f, s_rot_tr = 0.f;
  for (int i = 0; i < FB_CHUNK; ++i) {
    const int s = s0 + i;
    const float *y6 = yb + (size_t)s * 6;
    const float *g3 = gp + (size_t)s * 3;
    const float *o3 = go + (size_t)s * 3;
    if (s != 0) {
      SE3 Pe = build_pose(y6[0], y6[1], y6[2], y6[3], y6[4], y6[5]);
      SE3 Pg = build_pose(o3[0], o3[1], o3[2], g3[0], g3[1], g3[2]);
      Te = se3_mul(Te, Pe);
      Tg = se3_mul(Tg, Pg);
    }
    const float dx = Te.t[0] - Tg.t[0];
    const float dy = Te.t[1] - Tg.t[1];
    const float dz = Te.t[2] - Tg.t[2];
    s_sq_tr += dx * dx + dy * dy + dz * dz;
    s_abs_tr += fabsf(dx) + fabsf(dy) + fabsf(dz);
    s_rot_tr += geo_angle(Te, Tg);
  }

#pragma unroll
  for (int o = 32; o > 0; o >>= 1) {
    s_sq_pos += __shfl_xor(s_sq_pos, o, 64);
    s_abs_pos += __shfl_xor(s_abs_pos, o, 64);
    s_rot_odom += __shfl_xor(s_rot_odom, o, 64);
    s_sq_tr += __shfl_xor(s_sq_tr, o, 64);
    s_abs_tr += __shfl_xor(s_abs_tr, o, 64);
    s_rot_tr += __shfl_xor(s_rot_tr, o, 64);
  }
  if (lane == 0) {
    atomicAdd(&acc[0], (double)s_sq_pos);
    atomicAdd(&acc[1], (double)s_abs_pos);
    atomicAdd(&acc[2], (double)s_rot_odom);
    atomicAdd(&acc[3], (double)s_sq_tr);
    atomicAdd(&acc[4], (double)s_abs_tr);
    atomicAdd(&acc[5], (double)s_rot_tr);
  }
}

__global__ void init_acc(double *acc) {
  const int i = threadIdx.x;
  if (i < 6) acc[i] = 0.0;
}

__global__ void finalize_acc(const double *__restrict__ acc,
                             float *__restrict__ out) {
  const double n3 = (double)NB * (double)NS * 3.0;
  const double n1 = (double)NB * (double)NS;
  const double odom = acc[2] / n1 + (acc[0] / n3 + acc[1] / n3);
  const double traj = acc[5] / n1 + (acc[3] / n3 + acc[4] / n3);
  out[0] = (float)(0.5 * odom + 0.5 * traj);
}

extern "C" void kernel_launch(void *const *d_in, const int *in_sizes, int n_in,
                              void *d_out, int out_size, void *d_ws,
                              size_t ws_size, hipStream_t stream) {
  const float *y_hat = (const float *)d_in[0];
  const float *gt_pos = (const float *)d_in[1];
  const float *gt_ori = (const float *)d_in[2];

  float *wsl = (float *)d_ws;
  const size_t wsl_elems = (size_t)NB * 10 * NS;
  float *aggs = wsl + wsl_elems;
  float *part1 = aggs + (size_t)NSEGB * 16;
  float *part2 = part1 + (size_t)NSEGB * 3;
  const size_t need = (wsl_elems + (size_t)NSEGB * 22) * sizeof(float);

  if (ws_size >= need) {
    k1_scan<<<NSEGB, K1_TPB, 0, stream>>>(y_hat, gt_pos, gt_ori, wsl, aggs,
                                          part1);
    k3_traj<<<NSEGB, K3_TPB, 0, stream>>>(wsl, aggs, part2);
    finalize_parts<<<1, FTPB, 0, stream>>>(part1, part2, (float *)d_out);
  } else {
    double *acc = (double *)d_ws;
    init_acc<<<1, 64, 0, stream>>>(acc);
    traj_loss_main<<<NB, FB_T, 0, stream>>>(y_hat, gt_pos, gt_ori, acc);
    finalize_acc<<<1, 1, 0, stream>>>(acc, (float *)d_out);
  }
}

// Round 12
// 24.210 us; speedup vs baseline: 1.2108x; 1.2108x over previous
//
#include <hip/hip_runtime.h>
#include <hip/hip_fp16.h>
#include <math.h>

#define NB 64
#define NS 4096
#define SEGS 8                   // segments per batch
#define TPB 256                  // k1 threads per block
#define CHUNK 2                  // k1 elements per thread (R10 best)
#define STEPS (NS / SEGS)        // 512 elements per segment
#define NWAVES (TPB / 64)        // 4
#define NSEGB (NB * SEGS)        // 512 blocks
#define K3_TPB 512
#define K3_W (K3_TPB / 64)
#define FTPB 512

// fallback (single-phase) params
#define FB_T 512
#define FB_CHUNK (NS / FB_T)
#define FB_W (FB_T / 64)

// ---------------- quaternion + translation rigid transform -----------------
struct Q {
  float w, x, y, z;
};
struct QT {
  Q q;
  float tx, ty, tz;
};

__device__ __forceinline__ Q qmul(const Q &a, const Q &b) {
  Q c;
  c.w = a.w * b.w - a.x * b.x - a.y * b.y - a.z * b.z;
  c.x = a.w * b.x + b.w * a.x + a.y * b.z - a.z * b.y;
  c.y = a.w * b.y + b.w * a.y + a.z * b.x - a.x * b.z;
  c.z = a.w * b.z + b.w * a.z + a.x * b.y - a.y * b.x;
  return c;
}

__device__ __forceinline__ Q qconj(const Q &q) {
  Q c;
  c.w = q.w;
  c.x = -q.x;
  c.y = -q.y;
  c.z = -q.z;
  return c;
}

__device__ __forceinline__ void qrot(const Q &q, float vx, float vy, float vz,
                                     float &ox, float &oy, float &oz) {
  const float tx = 2.f * (q.y * vz - q.z * vy);
  const float ty = 2.f * (q.z * vx - q.x * vz);
  const float tz = 2.f * (q.x * vy - q.y * vx);
  ox = vx + q.w * tx + (q.y * tz - q.z * ty);
  oy = vy + q.w * ty + (q.z * tx - q.x * tz);
  oz = vz + q.w * tz + (q.x * ty - q.y * tx);
}

__device__ __forceinline__ void q_id(Q &q) {
  q.w = 1.f;
  q.x = q.y = q.z = 0.f;
}

__device__ __forceinline__ void qt_id(QT &x) {
  q_id(x.q);
  x.tx = x.ty = x.tz = 0.f;
}

// c = a * b : q = qa*qb, t = rot(qa, tb) + ta
__device__ __forceinline__ QT qt_mul(const QT &a, const QT &b) {
  QT c;
  c.q = qmul(a.q, b.q);
  float rx, ry, rz;
  qrot(a.q, b.tx, b.ty, b.tz, rx, ry, rz);
  c.tx = rx + a.tx;
  c.ty = ry + a.ty;
  c.tz = rz + a.tz;
  return c;
}

__device__ __forceinline__ Q q_shfl_up(const Q &v, int delta) {
  Q y;
  y.w = __shfl_up(v.w, delta, 64);
  y.x = __shfl_up(v.x, delta, 64);
  y.y = __shfl_up(v.y, delta, 64);
  y.z = __shfl_up(v.z, delta, 64);
  return y;
}

// fast acos: Abramowitz-Stegun 4.4.45 style, |err| <= 6.7e-5 rad
__device__ __forceinline__ float fast_acosf(float x) {
  const float ax = fabsf(x);
  float p = fmaf(ax, -0.0187293f, 0.0742610f);
  p = fmaf(p, ax, -0.2121144f);
  p = fmaf(p, ax, 1.5707288f);
  const float r = sqrtf(fmaxf(1.f - ax, 0.f)) * p;
  return (x >= 0.f) ? r : (3.14159274f - r);
}

__device__ __forceinline__ float angle_from_cos(float cosv) {
  cosv = fminf(fmaxf(cosv, -1.f + 1e-6f), 1.f - 1e-6f);
  return fast_acosf(cosv);
}

// Euler xyz (R = Rz(c)*Ry(b)*Rx(a)) -> quaternion, via half angles
__device__ __forceinline__ Q euler_to_quat(float a, float b, float c) {
  float sa, ca, sb, cb, sc, cc;
  __sincosf(0.5f * a, &sa, &ca);
  __sincosf(0.5f * b, &sb, &cb);
  __sincosf(0.5f * c, &sc, &cc);
  Q q;
  q.w = cc * cb * ca + sc * sb * sa;
  q.x = cc * cb * sa - sc * sb * ca;
  q.y = cc * sb * ca + sc * cb * sa;
  q.z = sc * cb * ca - cc * sb * sa;
  return q;
}

__device__ __forceinline__ void block_reduce3_store(float v0, float v1,
                                                    float v2,
                                                    float *__restrict__ dst,
                                                    int lane, int wave,
                                                    int tid, int nwaves) {
#pragma unroll
  for (int o = 32; o > 0; o >>= 1) {
    v0 += __shfl_xor(v0, o, 64);
    v1 += __shfl_xor(v1, o, 64);
    v2 += __shfl_xor(v2, o, 64);
  }
  __shared__ float red[8][3];
  if (lane == 0) {
    red[wave][0] = v0;
    red[wave][1] = v1;
    red[wave][2] = v2;
  }
  __syncthreads();
  if (tid == 0) {
    float a = 0.f, b = 0.f, c = 0.f;
    for (int w = 0; w < nwaves; ++w) {
      a += red[w][0];
      b += red[w][1];
      c += red[w][2];
    }
    dst[0] = a;
    dst[1] = b;
    dst[2] = c;
  }
}

// ws layout (floats):
//   wsl   : NB * 8 * NS   per-step record (32 B):
//           plane0 float2[NS] q_rel as 4x half, plane1 float4[NS]
//           {ltx,lty,ltz,gtx}, plane2 float2[NS] {gty,gtz}
//   aggs  : NSEGB * 16    segment-end QT pairs (est 7 | pad | gt 7 | pad)
//   part1 : NSEGB * 3
//   part2 : NSEGB * 3

// ---------------- k1: dual-chain quaternion scan (decoupled KS) ------------
__global__ __launch_bounds__(TPB) void k1_scan(
    const float *__restrict__ y_hat, const float *__restrict__ gt_pos,
    const float *__restrict__ gt_ori, float *__restrict__ wsl,
    float *__restrict__ aggs, float *__restrict__ part1) {
  const int blk = blockIdx.x;
  const int b = blk >> 3;
  const int seg = blk & (SEGS - 1);
  const int tid = threadIdx.x;
  const int lane = tid & 63;
  const int wave = tid >> 6;
  const int s0 = seg * STEPS + tid * CHUNK;

  float s_sq = 0.f, s_abs = 0.f, s_rot = 0.f;

  QT P1e, P1g, P2e, P2g;
  {
    const float *y6 = y_hat + ((size_t)b * NS + s0) * 6;
    const float *g3 = gt_pos + ((size_t)b * NS + s0) * 3;
    const float *o3 = gt_ori + ((size_t)b * NS + s0) * 3;
    const float px = y6[3], py = y6[4], pz = y6[5];
    const float gx = g3[0], gy = g3[1], gz = g3[2];
    P1e.q = euler_to_quat(y6[0], y6[1], y6[2]);
    P1e.tx = px; P1e.ty = py; P1e.tz = pz;
    P1g.q = euler_to_quat(o3[0], o3[1], o3[2]);
    P1g.tx = gx; P1g.ty = gy; P1g.tz = gz;
    const float dx = px - gx, dy = py - gy, dz = pz - gz;
    s_sq += dx * dx + dy * dy + dz * dz;
    s_abs += fabsf(dx) + fabsf(dy) + fabsf(dz);
    const float d = P1e.q.w * P1g.q.w + P1e.q.x * P1g.q.x +
                    P1e.q.y * P1g.q.y + P1e.q.z * P1g.q.z;
    s_rot += angle_from_cos(2.f * d * d - 1.f);
    if (s0 == 0) {  // shifted[0] = identity
      qt_id(P1e);
      qt_id(P1g);
    }
  }
  {
    const int s1 = s0 + 1;
    const float *y6 = y_hat + ((size_t)b * NS + s1) * 6;
    const float *g3 = gt_pos + ((size_t)b * NS + s1) * 3;
    const float *o3 = gt_ori + ((size_t)b * NS + s1) * 3;
    const float px = y6[3], py = y6[4], pz = y6[5];
    const float gx = g3[0], gy = g3[1], gz = g3[2];
    P2e.q = euler_to_quat(y6[0], y6[1], y6[2]);
    P2e.tx = px; P2e.ty = py; P2e.tz = pz;
    P2g.q = euler_to_quat(o3[0], o3[1], o3[2]);
    P2g.tx = gx; P2g.ty = gy; P2g.tz = gz;
    const float dx = px - gx, dy = py - gy, dz = pz - gz;
    s_sq += dx * dx + dy * dy + dz * dz;
    s_abs += fabsf(dx) + fabsf(dy) + fabsf(dz);
    const float d = P2e.q.w * P2g.q.w + P2e.q.x * P2g.q.x +
                    P2e.q.y * P2g.q.y + P2e.q.z * P2g.q.z;
    s_rot += angle_from_cos(2.f * d * d - 1.f);
  }

  // ---- thread aggregates (quat + translation separately)
  Q Aqe = qmul(P1e.q, P2e.q);
  Q Aqg = qmul(P1g.q, P2g.q);
  float tAex, tAey, tAez, tAgx, tAgy, tAgz;
  {
    float rx, ry, rz;
    qrot(P1e.q, P2e.tx, P2e.ty, P2e.tz, rx, ry, rz);
    tAex = P1e.tx + rx; tAey = P1e.ty + ry; tAez = P1e.tz + rz;
    qrot(P1g.q, P2g.tx, P2g.ty, P2g.tz, rx, ry, rz);
    tAgx = P1g.tx + rx; tAgy = P1g.ty + ry; tAgz = P1g.tz + rz;
  }

  // ---- decoupled wave Kogge-Stone: quats only (16 VALU/round/chain)
  Q Iqe = Aqe, Iqg = Aqg;
#pragma unroll
  for (int o = 1; o < 64; o <<= 1) {
    Q pe = q_shfl_up(Iqe, o);
    Q pg = q_shfl_up(Iqg, o);
    if (lane >= o) {
      Iqe = qmul(pe, Iqe);
      Iqg = qmul(pg, Iqg);
    }
  }

  // lane-exclusive quat prefixes
  Q Eqe = q_shfl_up(Iqe, 1);
  Q Eqg = q_shfl_up(Iqg, 1);
  if (lane == 0) {
    q_id(Eqe);
    q_id(Eqg);
  }

  // rotate aggregate translations into wave frame, then 3-float add-scan
  float vex, vey, vez, vgx, vgy, vgz;
  qrot(Eqe, tAex, tAey, tAez, vex, vey, vez);
  qrot(Eqg, tAgx, tAgy, tAgz, vgx, vgy, vgz);
#pragma unroll
  for (int o = 1; o < 64; o <<= 1) {
    const float a0 = __shfl_up(vex, o, 64);
    const float a1 = __shfl_up(vey, o, 64);
    const float a2 = __shfl_up(vez, o, 64);
    const float b0 = __shfl_up(vgx, o, 64);
    const float b1 = __shfl_up(vgy, o, 64);
    const float b2 = __shfl_up(vgz, o, 64);
    if (lane >= o) {
      vex += a0; vey += a1; vez += a2;
      vgx += b0; vgy += b1; vgz += b2;
    }
  }
  // inclusive wave-scan now: {Iqe,(vex,vey,vez)}, {Iqg,(vgx,vgy,vgz)}

  // lane-exclusive translations
  float Etex = __shfl_up(vex, 1, 64);
  float Etey = __shfl_up(vey, 1, 64);
  float Etez = __shfl_up(vez, 1, 64);
  float Etgx = __shfl_up(vgx, 1, 64);
  float Etgy = __shfl_up(vgy, 1, 64);
  float Etgz = __shfl_up(vgz, 1, 64);
  if (lane == 0) {
    Etex = Etey = Etez = 0.f;
    Etgx = Etgy = Etgz = 0.f;
  }

  // ---- cross-wave prefix (full QT via LDS, unchanged)
  __shared__ float aggE[NWAVES][8];
  __shared__ float aggG[NWAVES][8];
  if (lane == 63) {
    aggE[wave][0] = Iqe.w; aggE[wave][1] = Iqe.x;
    aggE[wave][2] = Iqe.y; aggE[wave][3] = Iqe.z;
    aggE[wave][4] = vex; aggE[wave][5] = vey; aggE[wave][6] = vez;
    aggG[wave][0] = Iqg.w; aggG[wave][1] = Iqg.x;
    aggG[wave][2] = Iqg.y; aggG[wave][3] = Iqg.z;
    aggG[wave][4] = vgx; aggG[wave][5] = vgy; aggG[wave][6] = vgz;
  }
  __syncthreads();

  QT We, Wg;
  qt_id(We);
  qt_id(Wg);
  for (int w = 0; w < wave; ++w) {
    QT ae, ag;
    ae.q.w = aggE[w][0]; ae.q.x = aggE[w][1];
    ae.q.y = aggE[w][2]; ae.q.z = aggE[w][3];
    ae.tx = aggE[w][4]; ae.ty = aggE[w][5]; ae.tz = aggE[w][6];
    ag.q.w = aggG[w][0]; ag.q.x = aggG[w][1];
    ag.q.y = aggG[w][2]; ag.q.z = aggG[w][3];
    ag.tx = aggG[w][4]; ag.ty = aggG[w][5]; ag.tz = aggG[w][6];
    We = qt_mul(We, ae);
    Wg = qt_mul(Wg, ag);
  }

  // thread's block-exclusive base, walk the 2 held poses
  QT Ee, Eg;
  Ee.q = Eqe; Ee.tx = Etex; Ee.ty = Etey; Ee.tz = Etez;
  Eg.q = Eqg; Eg.tx = Etgx; Eg.ty = Etgy; Eg.tz = Etgz;
  QT Be = qt_mul(We, Ee);
  QT Bg = qt_mul(Wg, Eg);

  QT L1e = qt_mul(Be, P1e);
  QT L1g = qt_mul(Bg, P1g);
  QT L2e = qt_mul(L1e, P2e);
  QT L2g = qt_mul(L1g, P2g);

  // ---- per-step compressed records (32 B: half4 q_rel + 6 fp32 t)
  float *base = wsl + (size_t)b * 8 * NS;
  float2 *q2 = (float2 *)base;
  float4 *lt4 = (float4 *)(base + (size_t)2 * NS);
  float2 *g2 = (float2 *)(base + (size_t)6 * NS);
  {
    const Q qm = qmul(L1e.q, qconj(L1g.q));
    union { __half2 h[2]; float2 f; } pk;
    pk.h[0] = __floats2half2_rn(qm.w, qm.x);
    pk.h[1] = __floats2half2_rn(qm.y, qm.z);
    q2[s0] = pk.f;
    lt4[s0] = make_float4(L1e.tx, L1e.ty, L1e.tz, L1g.tx);
    g2[s0] = make_float2(L1g.ty, L1g.tz);
  }
  {
    const Q qm = qmul(L2e.q, qconj(L2g.q));
    union { __half2 h[2]; float2 f; } pk;
    pk.h[0] = __floats2half2_rn(qm.w, qm.x);
    pk.h[1] = __floats2half2_rn(qm.y, qm.z);
    q2[s0 + 1] = pk.f;
    lt4[s0 + 1] = make_float4(L2e.tx, L2e.ty, L2e.tz, L2g.tx);
    g2[s0 + 1] = make_float2(L2g.ty, L2g.tz);
  }

  // segment aggregate (QT pair, fp32) for k3's prefix walk
  if (tid == TPB - 1) {
    float *ag = aggs + (size_t)blk * 16;
    ag[0] = L2e.q.w; ag[1] = L2e.q.x; ag[2] = L2e.q.y; ag[3] = L2e.q.z;
    ag[4] = L2e.tx; ag[5] = L2e.ty; ag[6] = L2e.tz;
    ag[8] = L2g.q.w; ag[9] = L2g.q.x; ag[10] = L2g.q.y; ag[11] = L2g.q.z;
    ag[12] = L2g.tx; ag[13] = L2g.ty; ag[14] = L2g.tz;
  }

  block_reduce3_store(s_sq, s_abs, s_rot, part1 + (size_t)blk * 3, lane, wave,
                      tid, NWAVES);
}

// ---------------- k3: contracted traj terms -------------------------------
__global__ __launch_bounds__(K3_TPB) void k3_traj(const float *__restrict__ wsl,
                                                  const float *__restrict__ aggs,
                                                  float *__restrict__ part2) {
  const int blk = blockIdx.x;
  const int b = blk >> 3;
  const int seg = blk & (SEGS - 1);
  const int tid = threadIdx.x;
  const int lane = tid & 63;
  const int wave = tid >> 6;
  const int s = seg * STEPS + tid;

  // segment-exclusive prefixes (block-uniform walk over <=7 aggregates)
  QT Ee, Eg;
  qt_id(Ee);
  qt_id(Eg);
  const float *abase = aggs + (size_t)(b * SEGS) * 16;
  for (int w = 0; w < seg; ++w) {
    const float *ag = abase + (size_t)w * 16;
    QT ae, agm;
    ae.q.w = ag[0]; ae.q.x = ag[1]; ae.q.y = ag[2]; ae.q.z = ag[3];
    ae.tx = ag[4]; ae.ty = ag[5]; ae.tz = ag[6];
    agm.q.w = ag[8]; agm.q.x = ag[9]; agm.q.y = ag[10]; agm.q.z = ag[11];
    agm.tx = ag[12]; agm.ty = ag[13]; agm.tz = ag[14];
    Ee = qt_mul(Ee, ae);
    Eg = qt_mul(Eg, agm);
  }

  // block-uniform u = conj(q_Eg) * q_Ee ; dt0 = Ee.t - Eg.t
  const Q u = qmul(qconj(Eg.q), Ee.q);
  const float dt0x = Ee.tx - Eg.tx;
  const float dt0y = Ee.ty - Eg.ty;
  const float dt0z = Ee.tz - Eg.tz;

  // per-step record
  const float *base = wsl + (size_t)b * 8 * NS;
  const float2 *q2 = (const float2 *)base;
  const float4 *lt4 = (const float4 *)(base + (size_t)2 * NS);
  const float2 *g2 = (const float2 *)(base + (size_t)6 * NS);

  union { float2 f; __half2 h[2]; } pk;
  pk.f = q2[s];
  const float2 wx = __half22float2(pk.h[0]);
  const float2 yz = __half22float2(pk.h[1]);
  const float mw = wx.x, mx = wx.y, my = yz.x, mz = yz.y;

  const float4 lt = lt4[s];
  const float2 gv = g2[s];

  // rotation: wd = w(u * q_rel); cos = 2*wd^2 - 1
  const float wd = u.w * mw - u.x * mx - u.y * my - u.z * mz;
  float s_rot = angle_from_cos(2.f * wd * wd - 1.f);

  // position: d = rot(Ee.q, lt) - rot(Eg.q, gt) + dt0
  float ux, uy, uz, vx, vy, vz;
  qrot(Ee.q, lt.x, lt.y, lt.z, ux, uy, uz);
  qrot(Eg.q, lt.w, gv.x, gv.y, vx, vy, vz);
  const float dx = ux - vx + dt0x;
  const float dy = uy - vy + dt0y;
  const float dz = uz - vz + dt0z;

  float s_sq = dx * dx + dy * dy + dz * dz;
  float s_abs = fabsf(dx) + fabsf(dy) + fabsf(dz);

  block_reduce3_store(s_sq, s_abs, s_rot, part2 + (size_t)blk * 3, lane, wave,
                      tid, K3_W);
}

__global__ __launch_bounds__(FTPB) void finalize_parts(
    const float *__restrict__ part1, const float *__restrict__ part2,
    float *__restrict__ out) {
  const int tid = threadIdx.x;
  const int lane = tid & 63;
  const int wave = tid >> 6;

  float v[6];
#pragma unroll
  for (int k = 0; k < 3; ++k) {
    v[k] = part1[(size_t)tid * 3 + k];
    v[3 + k] = part2[(size_t)tid * 3 + k];
  }
#pragma unroll
  for (int o = 32; o > 0; o >>= 1) {
#pragma unroll
    for (int k = 0; k < 6; ++k) v[k] += __shfl_xor(v[k], o, 64);
  }
  __shared__ float red[FTPB / 64][6];
  if (lane == 0) {
#pragma unroll
    for (int k = 0; k < 6; ++k) red[wave][k] = v[k];
  }
  __syncthreads();
  if (tid == 0) {
    double a[6];
#pragma unroll
    for (int k = 0; k < 6; ++k) {
      double t = 0.0;
#pragma unroll
      for (int w = 0; w < FTPB / 64; ++w) t += (double)red[w][k];
      a[k] = t;
    }
    const double n3 = (double)NB * (double)NS * 3.0;
    const double n1 = (double)NB * (double)NS;
    const double odom = a[2] / n1 + (a[0] / n3 + a[1] / n3);
    const double traj = a[5] / n1 + (a[3] / n3 + a[4] / n3);
    out[0] = (float)(0.5 * odom + 0.5 * traj);
  }
}

// ---------------- fallback single-phase path (matrices, tiny ws) -----------
struct SE3 {
  float r[9];
  float t[3];
};

__device__ __forceinline__ void se3_id(SE3 &x) {
#pragma unroll
  for (int i = 0; i < 9; ++i) x.r[i] = 0.f;
  x.r[0] = x.r[4] = x.r[8] = 1.f;
  x.t[0] = x.t[1] = x.t[2] = 0.f;
}

__device__ __forceinline__ SE3 se3_mul(const SE3 &a, const SE3 &b) {
  SE3 c;
#pragma unroll
  for (int i = 0; i < 3; ++i) {
#pragma unroll
    for (int j = 0; j < 3; ++j) {
      c.r[i * 3 + j] = fmaf(a.r[i * 3 + 0], b.r[0 * 3 + j],
                       fmaf(a.r[i * 3 + 1], b.r[1 * 3 + j],
                            a.r[i * 3 + 2] * b.r[2 * 3 + j]));
    }
    c.t[i] = fmaf(a.r[i * 3 + 0], b.t[0],
             fmaf(a.r[i * 3 + 1], b.t[1],
             fmaf(a.r[i * 3 + 2], b.t[2], a.t[i])));
  }
  return c;
}

__device__ __forceinline__ SE3 build_pose(float a, float b, float c,
                                          float tx, float ty, float tz) {
  float sa, ca, sb, cb, sc, cc;
  __sincosf(a, &sa, &ca);
  __sincosf(b, &sb, &cb);
  __sincosf(c, &sc, &cc);
  SE3 p;
  p.r[0] = cc * cb;
  p.r[1] = cc * sb * sa - sc * ca;
  p.r[2] = cc * sb * ca + sc * sa;
  p.r[3] = sc * cb;
  p.r[4] = sc * sb * sa + cc * ca;
  p.r[5] = sc * sb * ca - cc * sa;
  p.r[6] = -sb;
  p.r[7] = cb * sa;
  p.r[8] = cb * ca;
  p.t[0] = tx;
  p.t[1] = ty;
  p.t[2] = tz;
  return p;
}

__device__ __forceinline__ SE3 se3_shfl_up(const SE3 &x, int delta) {
  SE3 y;
#pragma unroll
  for (int i = 0; i < 9; ++i) y.r[i] = __shfl_up(x.r[i], delta, 64);
#pragma unroll
  for (int i = 0; i < 3; ++i) y.t[i] = __shfl_up(x.t[i], delta, 64);
  return y;
}

__device__ __forceinline__ float geo_angle(const SE3 &A, const SE3 &B) {
  float dot = 0.f;
#pragma unroll
  for (int k = 0; k < 9; ++k) dot = fmaf(A.r[k], B.r[k], dot);
  return angle_from_cos(0.5f * (dot - 1.f));
}

__global__ __launch_bounds__(FB_T) void traj_loss_main(
    const float *__restrict__ y_hat, const float *__restrict__ gt_pos,
    const float *__restrict__ gt_ori, double *__restrict__ acc) {
  const int b = blockIdx.x;
  const int tid = threadIdx.x;
  const int lane = tid & 63;
  const int wave = tid >> 6;
  const int s0 = tid * FB_CHUNK;

  const float *yb = y_hat + (size_t)b * NS * 6;
  const float *gp = gt_pos + (size_t)b * NS * 3;
  const float *go = gt_ori + (size_t)b * NS * 3;

  float s_sq_pos = 0.f, s_abs_pos = 0.f, s_rot_odom = 0.f;

  SE3 Le, Lg;
  se3_id(Le);
  se3_id(Lg);

  for (int i = 0; i < FB_CHUNK; ++i) {
    const int s = s0 + i;
    const float *y6 = yb + (size_t)s * 6;
    const float *g3 = gp + (size_t)s * 3;
    const float *o3 = go + (size_t)s * 3;
    const float px = y6[3], py = y6[4], pz = y6[5];
    const float gx = g3[0], gy = g3[1], gz = g3[2];

    SE3 Pe = build_pose(y6[0], y6[1], y6[2], px, py, pz);
    SE3 Pg = build_pose(o3[0], o3[1], o3[2], gx, gy, gz);

    const float dx = px - gx, dy = py - gy, dz = pz - gz;
    s_sq_pos += dx * dx + dy * dy + dz * dz;
    s_abs_pos += fabsf(dx) + fabsf(dy) + fabsf(dz);
    s_rot_odom += geo_angle(Pe, Pg);

    if (s != 0) {
      Le = se3_mul(Le, Pe);
      Lg = se3_mul(Lg, Pg);
    }
  }

  SE3 Ie = Le, Ig = Lg;
#pragma unroll
  for (int o = 1; o < 64; o <<= 1) {
    SE3 pe = se3_shfl_up(Ie, o);
    SE3 pg = se3_shfl_up(Ig, o);
    if (lane >= o) {
      Ie = se3_mul(pe, Ie);
      Ig = se3_mul(pg, Ig);
    }
  }

  __shared__ float aggE[FB_W][12];
  __shared__ float aggG[FB_W][12];
  if (lane == 63) {
#pragma unroll
    for (int k = 0; k < 9; ++k) {
      aggE[wave][k] = Ie.r[k];
      aggG[wave][k] = Ig.r[k];
    }
#pragma unroll
    for (int k = 0; k < 3; ++k) {
      aggE[wave][9 + k] = Ie.t[k];
      aggG[wave][9 + k] = Ig.t[k];
    }
  }
  __syncthreads();

  SE3 Te, Tg;
  se3_id(Te);
  se3_id(Tg);
  for (int w = 0; w < wave; ++w) {
    SE3 ae, ag;
#pragma unroll
    for (int k = 0; k < 9; ++k) {
      ae.r[k] = aggE[w][k];
      ag.r[k] = aggG[w][k];
    }
#pragma unroll
    for (int k = 0; k < 3; ++k) {
      ae.t[k] = aggE[w][9 + k];
      ag.t[k] = aggG[w][9 + k];
    }
    Te = se3_mul(Te, ae);
    Tg = se3_mul(Tg, ag);
  }

  SE3 Ee = se3_shfl_up(Ie, 1);
  SE3 Eg = se3_shfl_up(Ig, 1);
  if (lane == 0) {
    se3_id(Ee);
    se3_id(Eg);
  }
  Te = se3_mul(Te, Ee);
  Tg = se3_mul(Tg, Eg);

  float s_sq_tr = 0.f, s_abs_tr = 0.f, s_rot_tr = 0.f;
  for (int i = 0; i < FB_CHUNK; ++i) {
    const int s = s0 + i;
    const float *y6 = yb + (size_t)s * 6;
    const float *g3 = gp + (size_t)s * 3;
    const float *o3 = go + (size_t)s * 3;
    if (s != 0) {
      SE3 Pe = build_pose(y6[0], y6[1], y6[2], y6[3], y6[4], y6[5]);
      SE3 Pg = build_pose(o3[0], o3[1], o3[2], g3[0], g3[1], g3[2]);
      Te = se3_mul(Te, Pe);
      Tg = se3_mul(Tg, Pg);
    }
    const float dx = Te.t[0] - Tg.t[0];
    const float dy = Te.t[1] - Tg.t[1];
    const float dz = Te.t[2] - Tg.t[2];
    s_sq_tr += dx * dx + dy * dy + dz * dz;
    s_abs_tr += fabsf(dx) + fabsf(dy) + fabsf(dz);
    s_rot_tr += geo_angle(Te, Tg);
  }

#pragma unroll
  for (int o = 32; o > 0; o >>= 1) {
    s_sq_pos += __shfl_xor(s_sq_pos, o, 64);
    s_abs_pos += __shfl_xor(s_abs_pos, o, 64);
    s_rot_odom += __shfl_xor(s_rot_odom, o, 64);
    s_sq_tr += __shfl_xor(s_sq_tr, o, 64);
    s_abs_tr += __shfl_xor(s_abs_tr, o, 64);
    s_rot_tr += __shfl_xor(s_rot_tr, o, 64);
  }
  if (lane == 0) {
    atomicAdd(&acc[0], (double)s_sq_pos);
    atomicAdd(&acc[1], (double)s_abs_pos);
    atomicAdd(&acc[2], (double)s_rot_odom);
    atomicAdd(&acc[3], (double)s_sq_tr);
    atomicAdd(&acc[4], (double)s_abs_tr);
    atomicAdd(&acc[5], (double)s_rot_tr);
  }
}

__global__ void init_acc(double *acc) {
  const int i = threadIdx.x;
  if (i < 6) acc[i] = 0.0;
}

__global__ void finalize_acc(const double *__restrict__ acc,
                             float *__restrict__ out) {
  const double n3 = (double)NB * (double)NS * 3.0;
  const double n1 = (double)NB * (double)NS;
  const double odom = acc[2] / n1 + (acc[0] / n3 + acc[1] / n3);
  const double traj = acc[5] / n1 + (acc[3] / n3 + acc[4] / n3);
  out[0] = (float)(0.5 * odom + 0.5 * traj);
}

extern "C" void kernel_launch(void *const *d_in, const int *in_sizes, int n_in,
                              void *d_out, int out_size, void *d_ws,
                              size_t ws_size, hipStream_t stream) {
  const float *y_hat = (const float *)d_in[0];
  const float *gt_pos = (const float *)d_in[1];
  const float *gt_ori = (const float *)d_in[2];

  float *wsl = (float *)d_ws;
  const size_t wsl_elems = (size_t)NB * 8 * NS;
  float *aggs = wsl + wsl_elems;
  float *part1 = aggs + (size_t)NSEGB * 16;
  float *part2 = part1 + (size_t)NSEGB * 3;
  const size_t need = (wsl_elems + (size_t)NSEGB * 22) * sizeof(float);

  if (ws_size >= need) {
    k1_scan<<<NSEGB, TPB, 0, stream>>>(y_hat, gt_pos, gt_ori, wsl, aggs,
                                       part1);
    k3_traj<<<NSEGB, K3_TPB, 0, stream>>>(wsl, aggs, part2);
    finalize_parts<<<1, FTPB, 0, stream>>>(part1, part2, (float *)d_out);
  } else {
    double *acc = (double *)d_ws;
    init_acc<<<1, 64, 0, stream>>>(acc);
    traj_loss_main<<<NB, FB_T, 0, stream>>>(y_hat, gt_pos, gt_ori, acc);
    finalize_acc<<<1, 1, 0, stream>>>(acc, (float *)d_out);
  }
}